// Round 2
// baseline (133.498 us; speedup 1.0000x reference)
//
#include <hip/hip_runtime.h>

// Sparse banded conv: out[b,o,y,x] = bias[o] +
//   sum_{s<16, kh<3, kw<3} W[o,s,kh,kw] * X[b,(o+s)%64, y+kh, x+kw]
// X: (8,64,96,96) f32, W: (64,16,3,3) f32, b: (64,) f32, out: (8,64,94,94) f32

constexpr int IN_H = 96, IN_W = 96;
constexpr int OUT_H = 94, OUT_W = 94;
constexpr int NCH = 64;    // input channels
constexpr int NOC = 64;    // output channels
constexpr int NSUB = 16;   // s dimension
constexpr int TILE_X = 16, TILE_Y = 8;
constexpr int ROWS = TILE_Y + 2;  // 10
constexpr int COLS = TILE_X + 2;  // 18

__global__ __launch_bounds__(256, 2)
void sconv_kernel(const float* __restrict__ Xg, const float* __restrict__ Wg,
                  const float* __restrict__ Bg, float* __restrict__ Og)
{
    __shared__ float Xs[NCH][ROWS][COLS];   // 64*10*18*4 = 46080 B

    const int tid  = threadIdx.x;
    const int wave = tid >> 6;
    const int lane = tid & 63;
    const int xg   = lane & 7;   // 8 x-groups of 2 outputs -> 16 x
    const int yg   = lane >> 3;  // 8 y rows

    const int tx0 = blockIdx.x * TILE_X;
    const int ty0 = blockIdx.y * TILE_Y;
    const int b   = blockIdx.z;

    const float* __restrict__ Xb = Xg + (size_t)b * NCH * IN_H * IN_W;

    // ---- stage input tile: all 64 channels, 10x18 window, float2 loads ----
    for (int e = tid; e < NCH * ROWS * (COLS / 2); e += 256) {
        const int c  = e / (ROWS * (COLS / 2));
        const int rm = e - c * (ROWS * (COLS / 2));
        const int r  = rm / (COLS / 2);
        const int c2 = rm - r * (COLS / 2);
        int gy = ty0 + r;      if (gy > IN_H - 1) gy = IN_H - 1;  // clamp: edge tiles
        int gx = tx0 + 2 * c2; if (gx > IN_W - 2) gx = IN_W - 2;  // stays even -> 8B aligned
        const float2 v = *reinterpret_cast<const float2*>(Xb + (c * IN_H + gy) * IN_W + gx);
        Xs[c][r][2 * c2]     = v.x;
        Xs[c][r][2 * c2 + 1] = v.y;
    }
    __syncthreads();

    float acc[16][2];
#pragma unroll
    for (int i = 0; i < 16; ++i) { acc[i][0] = 0.f; acc[i][1] = 0.f; }

    // Wave w owns output channels [16w, 16w+16): weight addresses wave-uniform.
    const int o_base = __builtin_amdgcn_readfirstlane(wave << 4);

    // Channel-outer loop: each staged X window reused by up to 16 (o,s) pairs.
    for (int dd = 0; dd < 31; ++dd) {
        const int c = (o_base + dd) & 63;
        float xv[3][4];
#pragma unroll
        for (int r = 0; r < 3; ++r) {
#pragma unroll
            for (int q = 0; q < 4; ++q)
                xv[r][q] = Xs[c][yg + r][2 * xg + q];
        }
#pragma unroll
        for (int jp = 0; jp < 16; ++jp) {
            // valid pair iff s = dd - jp in [0,16); guard is wave-uniform (scalar branch)
            if ((unsigned)(dd - jp) < 16u) {
                const int o = o_base + jp;
                const int s = dd - jp;
                const float* __restrict__ wp = Wg + ((o * NSUB) + s) * 9;
#pragma unroll
                for (int kh = 0; kh < 3; ++kh) {
#pragma unroll
                    for (int kw = 0; kw < 3; ++kw) {
                        const float wv = wp[kh * 3 + kw];  // SGPR (s_load), uniform
                        acc[jp][0] = fmaf(wv, xv[kh][kw],     acc[jp][0]);
                        acc[jp][1] = fmaf(wv, xv[kh][kw + 1], acc[jp][1]);
                    }
                }
            }
        }
    }

    // ---- epilogue: bias + store (float2; offset provably even -> 8B aligned) ----
    const int y  = ty0 + yg;
    const int x0 = tx0 + 2 * xg;
    if (y < OUT_H && x0 < OUT_W) {
#pragma unroll
        for (int jp = 0; jp < 16; ++jp) {
            const int o  = o_base + jp;
            const float bv = Bg[o];
            float2 v;
            v.x = acc[jp][0] + bv;
            v.y = acc[jp][1] + bv;
            *reinterpret_cast<float2*>(Og + (((size_t)b * NOC + o) * OUT_H + y) * OUT_W + x0) = v;
        }
    }
}

extern "C" void kernel_launch(void* const* d_in, const int* in_sizes, int n_in,
                              void* d_out, int out_size, void* d_ws, size_t ws_size,
                              hipStream_t stream)
{
    const float* X = (const float*)d_in[0];
    const float* W = (const float*)d_in[1];
    const float* B = (const float*)d_in[2];
    float* O = (float*)d_out;

    const int batch = in_sizes[0] / (NCH * IN_H * IN_W);   // = 8
    dim3 grid((OUT_W + TILE_X - 1) / TILE_X,   // 6
              (OUT_H + TILE_Y - 1) / TILE_Y,   // 12
              batch);                          // 8
    sconv_kernel<<<grid, 256, 0, stream>>>(X, W, B, O);
}

// Round 5
// 126.490 us; speedup vs baseline: 1.0554x; 1.0554x over previous
//
#include <hip/hip_runtime.h>

// Sparse banded conv: out[b,o,y,x] = bias[o] +
//   sum_{s<16, kh<3, kw<3} W[o,s,kh,kw] * X[b,(o+s)%64, y+kh, x+kw]
// X: (8,64,96,96) f32, W: (64,16,3,3) f32, b: (64,) f32, out: (8,64,94,94) f32

constexpr int IN_H = 96, IN_W = 96;
constexpr int OUT_H = 94, OUT_W = 94;
constexpr int NCH = 64;
constexpr int NOC = 64;
constexpr int NSUB = 16;
constexpr int TILE_X = 16, TILE_Y = 4;
constexpr int ROWS = TILE_Y + 2;  // 6
constexpr int COLS = 19;          // 18 data + 1 pad (odd stride -> banks spread)

__global__ __launch_bounds__(256, 4)
void sconv_kernel(const float* __restrict__ Xg, const float* __restrict__ Wg,
                  const float* __restrict__ Bg, float* __restrict__ Og)
{
    __shared__ float Xs[NCH][ROWS][COLS];   // 64*6*19*4 = 29184 B

    const int tid  = threadIdx.x;
    const int wave = tid >> 6;
    const int lane = tid & 63;
    const int x    = lane & 15;   // 16 x positions, 1 output each
    const int y4   = lane >> 4;   // 4 y rows

    const int tx0 = blockIdx.x * TILE_X;
    const int ty0 = blockIdx.y * TILE_Y;
    const int b   = blockIdx.z;

    const float* __restrict__ Xb = Xg + (size_t)b * NCH * IN_H * IN_W;

    // ---- stage: 64 channels x 6 rows x 18 cols (as 9 float2/row) ----
    for (int e = tid; e < NCH * ROWS * 9; e += 256) {
        const int c  = e / (ROWS * 9);
        const int rm = e - c * (ROWS * 9);
        const int r  = rm / 9;
        const int c2 = rm - r * 9;
        int gy = ty0 + r;      if (gy > IN_H - 1) gy = IN_H - 1;   // clamp (edge tiles)
        int gx = tx0 + 2 * c2; if (gx > IN_W - 2) gx = IN_W - 2;   // even -> 8B aligned
        const float2 v = *reinterpret_cast<const float2*>(Xb + (c * IN_H + gy) * IN_W + gx);
        Xs[c][r][2 * c2]     = v.x;
        Xs[c][r][2 * c2 + 1] = v.y;
    }
    __syncthreads();

    float acc[16];
#pragma unroll
    for (int i = 0; i < 16; ++i) acc[i] = 0.f;

    // Wave w owns output channels [16w, 16w+16): weight addrs wave-uniform -> SGPR.
    const int o_base = __builtin_amdgcn_readfirstlane(wave << 4);

    // Channel-outer loop (dd NOT force-unrolled — known-good codegen path):
    // each staged X window reused by up to 16 (o,s) pairs. Guard is wave-uniform.
    for (int dd = 0; dd < 31; ++dd) {
        const int c = (o_base + dd) & 63;   // wave-uniform
        float xv[3][3];
#pragma unroll
        for (int r = 0; r < 3; ++r)
#pragma unroll
            for (int kw = 0; kw < 3; ++kw)
                xv[r][kw] = Xs[c][y4 + r][x + kw];
#pragma unroll
        for (int jp = 0; jp < 16; ++jp) {
            if ((unsigned)(dd - jp) < 16u) {   // s = dd-jp in [0,16): scalar branch
                const int o = o_base + jp;
                const int s = dd - jp;
                const float* __restrict__ wp = Wg + ((o * NSUB) + s) * 9;
#pragma unroll
                for (int kh = 0; kh < 3; ++kh)
#pragma unroll
                    for (int kw = 0; kw < 3; ++kw)
                        acc[jp] = fmaf(wp[kh * 3 + kw], xv[kh][kw], acc[jp]);
            }
        }
    }

    // ---- epilogue: bias + store ----
    const int y  = ty0 + y4;
    const int x0 = tx0 + x;
    if (y < OUT_H && x0 < OUT_W) {
#pragma unroll
        for (int jp = 0; jp < 16; ++jp) {
            const int o = o_base + jp;
            Og[(((size_t)b * NOC + o) * OUT_H + y) * OUT_W + x0] = acc[jp] + Bg[o];
        }
    }
}

extern "C" void kernel_launch(void* const* d_in, const int* in_sizes, int n_in,
                              void* d_out, int out_size, void* d_ws, size_t ws_size,
                              hipStream_t stream)
{
    const float* X = (const float*)d_in[0];
    const float* W = (const float*)d_in[1];
    const float* B = (const float*)d_in[2];
    float* O = (float*)d_out;

    const int batch = in_sizes[0] / (NCH * IN_H * IN_W);   // 8
    dim3 grid((OUT_W + TILE_X - 1) / TILE_X,   // 6
              (OUT_H + TILE_Y - 1) / TILE_Y,   // 24
              batch);                          // 8
    sconv_kernel<<<grid, 256, 0, stream>>>(X, W, B, O);
}

// Round 6
// 102.512 us; speedup vs baseline: 1.3023x; 1.2339x over previous
//
#include <hip/hip_runtime.h>

// out[b,o,y,x] = bias[o] + sum_{s<16,kh,kw} W[o,s,kh,kw] * X[b,(o+s)%64,y+kh,x+kw]
// MFMA formulation: 9 banded 64x64 matrices M[kh,kw][o][c], fp16, D = M · Xpatch.

typedef _Float16 f16;
typedef _Float16 f16x8 __attribute__((ext_vector_type(8)));
typedef float    f32x16 __attribute__((ext_vector_type(16)));

constexpr int IN_H = 96, IN_W = 96, OUT_H = 94, OUT_W = 94;
constexpr int NCH = 64, NOC = 64, NSUB = 16, BATCH = 8;
constexpr int NTILES = BATCH * OUT_H * 3;            // (b, y, xg) ; xg: 3 groups of 32 px
constexpr size_t A_BYTES   = 2ull * 9 * 4 * 64 * 16; // [oh][khw][cs][lane] 16B granules = 73728
constexpr size_t XN_ELEMS  = (size_t)BATCH * IN_H * IN_W * NCH;  // fp16 NHWC
constexpr size_t XN_OFF    = A_BYTES;
constexpr size_t WS_NEEDED = XN_OFF + XN_ELEMS * 2 + 1024;       // +pad for x=96..97 halo reads

// ---- prologue 1: band matrices in exact A-fragment lane layout -------------
// A-frag (32x32x16, A = 32 rows(o) x 16 k(c)): lane l holds row o=(l&31),
// k = (l>>5)*8 + j  ->  granule (oh,khw,cs,lane) = 8 fp16.
__global__ void build_a_k(const float* __restrict__ W, f16* __restrict__ Ah)
{
    const int e = blockIdx.x * 256 + threadIdx.x;      // 4608 granules
    if (e >= 2 * 9 * 4 * 64) return;
    const int lane = e & 63;
    const int r    = e >> 6;          // ((oh*9 + khw)*4 + cs)
    const int cs   = r & 3;
    const int khw  = (r >> 2) % 9;
    const int oh   = (r >> 2) / 9;
    const int kh = khw / 3, kw = khw % 3;
    const int o  = oh * 32 + (lane & 31);
    const int cb = cs * 16 + (lane >> 5) * 8;
    f16 v[8];
#pragma unroll
    for (int j = 0; j < 8; ++j) {
        const int c = cb + j;
        const int s = (c - o) & 63;
        v[j] = (s < NSUB) ? (f16)W[((o * NSUB + s) * 3 + kh) * 3 + kw] : (f16)0.f;
    }
    *reinterpret_cast<f16x8*>(Ah + (size_t)e * 8) = *reinterpret_cast<f16x8*>(v);
}

// ---- prologue 2: NCHW fp32 -> NHWC fp16 ------------------------------------
__global__ void transpose_k(const float* __restrict__ X, f16* __restrict__ Xn)
{
    const int id = blockIdx.x;                  // (b, y, xt)
    const int xt = id % 3;
    const int ym = id / 3;
    const int y  = ym % IN_H;
    const int b  = ym / IN_H;
    const int x  = xt * 32 + (threadIdx.x & 31);
    const int c0 = (threadIdx.x >> 5) * 8;
    const float* __restrict__ xp = X + (((size_t)(b * NCH + c0) * IN_H + y) * IN_W + x);
    f16 v[8];
#pragma unroll
    for (int i = 0; i < 8; ++i)
        v[i] = (f16)xp[(size_t)i * IN_H * IN_W];          // coalesced per c-row
    *reinterpret_cast<f16x8*>(Xn + ((size_t)(b * IN_H + y) * IN_W + x) * NCH + c0) =
        *reinterpret_cast<f16x8*>(v);
}

// ---- main: A resident in VGPRs, B streamed from L2, no LDS -----------------
__global__ __launch_bounds__(256, 2)
void sconv_mfma(const f16* __restrict__ Ah, const f16* __restrict__ Xn,
                const float* __restrict__ Bg, float* __restrict__ Og)
{
    const int tid  = threadIdx.x;
    const int wave = tid >> 6;
    const int lane = tid & 63;
    const int oh   = wave & 1;          // o-half: 32 channels
    const int pair = wave >> 1;         // 2 wave-pairs per block share a tile stream
    const int px   = lane & 31;
    const int kg   = lane >> 5;

    // A fragments for this o-half: 9 khw x 4 c-steps, 16B/lane each (144 VGPR)
    f16x8 A[9][4];
    {
        const f16* Ab = Ah + (size_t)oh * 9 * 4 * 64 * 8;
#pragma unroll
        for (int khw = 0; khw < 9; ++khw)
#pragma unroll
            for (int cs = 0; cs < 4; ++cs)
                A[khw][cs] = *reinterpret_cast<const f16x8*>(
                    Ab + (((size_t)khw * 4 + cs) * 64 + lane) * 8);
    }
    // bias, preloaded in C/D row order
    float bv[16];
#pragma unroll
    for (int r = 0; r < 16; ++r)
        bv[r] = Bg[oh * 32 + (r & 3) + 8 * (r >> 2) + 4 * kg];

    for (int t = blockIdx.x * 2 + pair; t < NTILES; t += gridDim.x * 2) {
        const int b   = t / (OUT_H * 3);
        const int rem = t - b * (OUT_H * 3);
        const int y   = rem / 3;
        const int xg  = rem - y * 3;
        const int x0  = xg * 32;

        f32x16 acc;
#pragma unroll
        for (int r = 0; r < 16; ++r) acc[r] = 0.f;

#pragma unroll
        for (int kh = 0; kh < 3; ++kh) {
            const f16* rp = Xn + ((size_t)(b * IN_H + (y + kh)) * IN_W) * NCH;
#pragma unroll
            for (int kw = 0; kw < 3; ++kw) {
                // B-frag: col=px, k=(l>>5)*8+j -> c = cs*16 + kg*8 + j
                const f16* cp = rp + (size_t)(x0 + kw + px) * NCH + kg * 8;
                f16x8 bf[4];
#pragma unroll
                for (int cs = 0; cs < 4; ++cs)
                    bf[cs] = *reinterpret_cast<const f16x8*>(cp + cs * 16);
#pragma unroll
                for (int cs = 0; cs < 4; ++cs)
                    acc = __builtin_amdgcn_mfma_f32_32x32x16_f16(
                              A[kh * 3 + kw][cs], bf[cs], acc, 0, 0, 0);
            }
        }

        const int x = x0 + px;
        if (x < OUT_W) {
#pragma unroll
            for (int r = 0; r < 16; ++r) {
                const int o = oh * 32 + (r & 3) + 8 * (r >> 2) + 4 * kg;
                Og[(((size_t)b * NOC + o) * OUT_H + y) * OUT_W + x] = acc[r] + bv[r];
            }
        }
    }
}

// ---- fallback (round-5 proven VALU kernel) if ws too small -----------------
constexpr int TILE_X = 16, TILE_Y = 4, ROWS = TILE_Y + 2, COLS = 19;
__global__ __launch_bounds__(256, 4)
void sconv_kernel(const float* __restrict__ Xg, const float* __restrict__ Wg,
                  const float* __restrict__ Bg, float* __restrict__ Og)
{
    __shared__ float Xs[NCH][ROWS][COLS];
    const int tid = threadIdx.x, wave = tid >> 6, lane = tid & 63;
    const int x = lane & 15, y4 = lane >> 4;
    const int tx0 = blockIdx.x * TILE_X, ty0 = blockIdx.y * TILE_Y, b = blockIdx.z;
    const float* __restrict__ Xb = Xg + (size_t)b * NCH * IN_H * IN_W;
    for (int e = tid; e < NCH * ROWS * 9; e += 256) {
        const int c = e / (ROWS * 9), rm = e - c * (ROWS * 9), r = rm / 9, c2 = rm - r * 9;
        int gy = ty0 + r;      if (gy > IN_H - 1) gy = IN_H - 1;
        int gx = tx0 + 2 * c2; if (gx > IN_W - 2) gx = IN_W - 2;
        const float2 v = *reinterpret_cast<const float2*>(Xb + (c * IN_H + gy) * IN_W + gx);
        Xs[c][r][2 * c2] = v.x; Xs[c][r][2 * c2 + 1] = v.y;
    }
    __syncthreads();
    float acc[16];
#pragma unroll
    for (int i = 0; i < 16; ++i) acc[i] = 0.f;
    const int o_base = __builtin_amdgcn_readfirstlane(wave << 4);
    for (int dd = 0; dd < 31; ++dd) {
        const int c = (o_base + dd) & 63;
        float xv[3][3];
#pragma unroll
        for (int r = 0; r < 3; ++r)
#pragma unroll
            for (int kw = 0; kw < 3; ++kw) xv[r][kw] = Xs[c][y4 + r][x + kw];
#pragma unroll
        for (int jp = 0; jp < 16; ++jp)
            if ((unsigned)(dd - jp) < 16u) {
                const float* __restrict__ wp = Wg + (((o_base + jp) * NSUB) + (dd - jp)) * 9;
#pragma unroll
                for (int kh = 0; kh < 3; ++kh)
#pragma unroll
                    for (int kw = 0; kw < 3; ++kw)
                        acc[jp] = fmaf(wp[kh * 3 + kw], xv[kh][kw], acc[jp]);
            }
    }
    const int y = ty0 + y4, xo = tx0 + x;
    if (y < OUT_H && xo < OUT_W)
#pragma unroll
        for (int jp = 0; jp < 16; ++jp) {
            const int o = o_base + jp;
            Og[(((size_t)b * NOC + o) * OUT_H + y) * OUT_W + xo] = acc[jp] + Bg[o];
        }
}

extern "C" void kernel_launch(void* const* d_in, const int* in_sizes, int n_in,
                              void* d_out, int out_size, void* d_ws, size_t ws_size,
                              hipStream_t stream)
{
    const float* X = (const float*)d_in[0];
    const float* W = (const float*)d_in[1];
    const float* B = (const float*)d_in[2];
    float* O = (float*)d_out;

    if (ws_size < WS_NEEDED) {   // fallback: proven VALU kernel
        dim3 grid((OUT_W + TILE_X - 1) / TILE_X, (OUT_H + TILE_Y - 1) / TILE_Y, BATCH);
        sconv_kernel<<<grid, 256, 0, stream>>>(X, W, B, O);
        return;
    }

    f16* Ah = (f16*)d_ws;
    f16* Xn = (f16*)((char*)d_ws + XN_OFF);

    build_a_k<<<18, 256, 0, stream>>>(W, Ah);
    transpose_k<<<BATCH * IN_H * 3, 256, 0, stream>>>(X, Xn);
    sconv_mfma<<<512, 256, 0, stream>>>(Ah, Xn, B, O);
}

// Round 7
// 100.088 us; speedup vs baseline: 1.3338x; 1.0242x over previous
//
#include <hip/hip_runtime.h>

// out[b,o,y,x] = bias[o] + sum_{s<16,kh,kw} W[o,s,kh,kw] * X[b,(o+s)%64,y+kh,x+kw]
// MFMA: 9 banded 64x64 matrices, fp16. Band touches only 6 of 8 (oh,cs) 32x16
// blocks: oh0 -> cs{0,1,2}, oh1 -> cs{0,2,3} -> 27 fragments / o-half.

typedef _Float16 f16;
typedef _Float16 f16x8 __attribute__((ext_vector_type(8)));
typedef float    f32x16 __attribute__((ext_vector_type(16)));

constexpr int IN_H = 96, IN_W = 96, OUT_H = 94, OUT_W = 94;
constexpr int NCH = 64, NOC = 64, NSUB = 16, BATCH = 8;
constexpr int NSTRIP = BATCH * 3;                    // (b,xg) column strips
constexpr int NTILES = NSTRIP * OUT_H;               // 2256, ordered (strip, y)
constexpr size_t A_BYTES  = 2ull * 27 * 64 * 16;     // 2 oh x 27 frags x 64 lanes x 16B
constexpr size_t XN_ELEMS = (size_t)BATCH * IN_H * IN_W * NCH;   // fp16 NHWC
constexpr size_t XN_OFF   = A_BYTES;
constexpr size_t WS_NEEDED = XN_OFF + XN_ELEMS * 2 + 1024;       // pad: x=96/97 halo reads

// ---- prologue 1: band matrices, A-frag lane layout, zero-blocks skipped ----
// A-frag (32x32x16): lane l holds row o=(l&31), k=(l>>5)*8+j.
__global__ void build_a_k(const float* __restrict__ W, f16* __restrict__ Ah)
{
    const int e = blockIdx.x * 256 + threadIdx.x;     // 2*27*64 = 3456 granules
    if (e >= 2 * 27 * 64) return;
    const int lane = e & 63;
    const int r    = e >> 6;          // oh*27 + khw*3 + j
    const int j    = r % 3;
    const int khw  = (r / 3) % 9;
    const int oh   = r / 27;
    const int cs   = oh ? (j == 0 ? 0 : j + 1) : j;   // oh0:{0,1,2} oh1:{0,2,3}
    const int kh = khw / 3, kw = khw % 3;
    const int o  = oh * 32 + (lane & 31);
    const int cb = cs * 16 + (lane >> 5) * 8;
    f16 v[8];
#pragma unroll
    for (int jj = 0; jj < 8; ++jj) {
        const int c = cb + jj;
        const int s = (c - o) & 63;
        v[jj] = (s < NSUB) ? (f16)W[((o * NSUB + s) * 3 + kh) * 3 + kw] : (f16)0.f;
    }
    *reinterpret_cast<f16x8*>(Ah + (size_t)e * 8) = *reinterpret_cast<f16x8*>(v);
}

// ---- prologue 2: NCHW fp32 -> NHWC fp16 ------------------------------------
__global__ void transpose_k(const float* __restrict__ X, f16* __restrict__ Xn)
{
    const int id = blockIdx.x;                  // (b, y, xt)
    const int xt = id % 3;
    const int ym = id / 3;
    const int y  = ym % IN_H;
    const int b  = ym / IN_H;
    const int x  = xt * 32 + (threadIdx.x & 31);
    const int c0 = (threadIdx.x >> 5) * 8;
    const float* __restrict__ xp = X + (((size_t)(b * NCH + c0) * IN_H + y) * IN_W + x);
    f16 v[8];
#pragma unroll
    for (int i = 0; i < 8; ++i)
        v[i] = (f16)xp[(size_t)i * IN_H * IN_W];
    *reinterpret_cast<f16x8*>(Xn + ((size_t)(b * IN_H + y) * IN_W + x) * NCH + c0) =
        *reinterpret_cast<f16x8*>(v);
}

// ---- main: A resident in VGPRs, B from L1/L2, XCD-chunked tiles ------------
__global__ __launch_bounds__(256, 2)
void sconv_mfma(const f16* __restrict__ Ah, const f16* __restrict__ Xn,
                const float* __restrict__ Bg, float* __restrict__ Og)
{
    const int tid  = threadIdx.x;
    const int wave = tid >> 6;
    const int lane = tid & 63;
    const int oh   = wave & 1;
    const int px   = lane & 31;
    const int kg   = lane >> 5;

    // XCD-bijective swizzle: 1128 blocks = 8 XCDs x 141 contiguous chunks.
    const int wg = (blockIdx.x & 7) * 141 + (blockIdx.x >> 3);
    const int pairIdx = wg * 2 + (wave >> 1);         // in [0, 2256): (strip, y)
    const int strip = pairIdx / OUT_H;
    const int y     = pairIdx - strip * OUT_H;
    const int b     = strip / 3;
    const int xg    = strip - b * 3;
    const int x0    = xg * 32;

    // A fragments: 27 nonzero (khw, j) per o-half, 16B/lane (108 VGPR)
    f16x8 A[9][3];
    {
        const f16* Ab = Ah + (size_t)oh * 27 * 64 * 8;
#pragma unroll
        for (int khw = 0; khw < 9; ++khw)
#pragma unroll
            for (int j = 0; j < 3; ++j)
                A[khw][j] = *reinterpret_cast<const f16x8*>(
                    Ab + (((size_t)khw * 3 + j) * 64 + lane) * 8);
    }
    // B c-offsets (f16 elems) for the 3 live c-blocks of this o-half
    int co[3];
    co[0] = 0; co[1] = oh ? 32 : 16; co[2] = oh ? 48 : 32;

    // acc = bias (C/D row mapping: o = oh*32 + (r&3) + 8*(r>>2) + 4*kg)
    f32x16 acc;
#pragma unroll
    for (int r = 0; r < 16; ++r)
        acc[r] = Bg[oh * 32 + (r & 3) + 8 * (r >> 2) + 4 * kg];

#pragma unroll
    for (int kh = 0; kh < 3; ++kh) {
        const f16* rp = Xn + ((size_t)(b * IN_H + (y + kh)) * IN_W) * NCH;
#pragma unroll
        for (int kw = 0; kw < 3; ++kw) {
            const f16* cp = rp + (size_t)(x0 + kw + px) * NCH + kg * 8;
            f16x8 bf[3];
#pragma unroll
            for (int j = 0; j < 3; ++j)
                bf[j] = *reinterpret_cast<const f16x8*>(cp + co[j]);
#pragma unroll
            for (int j = 0; j < 3; ++j)
                acc = __builtin_amdgcn_mfma_f32_32x32x16_f16(
                          A[kh * 3 + kw][j], bf[j], acc, 0, 0, 0);
        }
    }

    const int x = x0 + px;
    if (x < OUT_W) {
#pragma unroll
        for (int r = 0; r < 16; ++r) {
            const int o = oh * 32 + (r & 3) + 8 * (r >> 2) + 4 * kg;
            Og[(((size_t)b * NOC + o) * OUT_H + y) * OUT_W + x] = acc[r];
        }
    }
}

// ---- fallback (round-5 proven VALU kernel) if ws too small -----------------
constexpr int TILE_X = 16, TILE_Y = 4, ROWS = TILE_Y + 2, COLS = 19;
__global__ __launch_bounds__(256, 4)
void sconv_kernel(const float* __restrict__ Xg, const float* __restrict__ Wg,
                  const float* __restrict__ Bg, float* __restrict__ Og)
{
    __shared__ float Xs[NCH][ROWS][COLS];
    const int tid = threadIdx.x, wave = tid >> 6, lane = tid & 63;
    const int x = lane & 15, y4 = lane >> 4;
    const int tx0 = blockIdx.x * TILE_X, ty0 = blockIdx.y * TILE_Y, b = blockIdx.z;
    const float* __restrict__ Xb = Xg + (size_t)b * NCH * IN_H * IN_W;
    for (int e = tid; e < NCH * ROWS * 9; e += 256) {
        const int c = e / (ROWS * 9), rm = e - c * (ROWS * 9), r = rm / 9, c2 = rm - r * 9;
        int gy = ty0 + r;      if (gy > IN_H - 1) gy = IN_H - 1;
        int gx = tx0 + 2 * c2; if (gx > IN_W - 2) gx = IN_W - 2;
        const float2 v = *reinterpret_cast<const float2*>(Xb + (c * IN_H + gy) * IN_W + gx);
        Xs[c][r][2 * c2] = v.x; Xs[c][r][2 * c2 + 1] = v.y;
    }
    __syncthreads();
    float acc[16];
#pragma unroll
    for (int i = 0; i < 16; ++i) acc[i] = 0.f;
    const int o_base = __builtin_amdgcn_readfirstlane(wave << 4);
    for (int dd = 0; dd < 31; ++dd) {
        const int c = (o_base + dd) & 63;
        float xv[3][3];
#pragma unroll
        for (int r = 0; r < 3; ++r)
#pragma unroll
            for (int kw = 0; kw < 3; ++kw) xv[r][kw] = Xs[c][y4 + r][x + kw];
#pragma unroll
        for (int jp = 0; jp < 16; ++jp)
            if ((unsigned)(dd - jp) < 16u) {
                const float* __restrict__ wp = Wg + (((o_base + jp) * NSUB) + (dd - jp)) * 9;
#pragma unroll
                for (int kh = 0; kh < 3; ++kh)
#pragma unroll
                    for (int kw = 0; kw < 3; ++kw)
                        acc[jp] = fmaf(wp[kh * 3 + kw], xv[kh][kw], acc[jp]);
            }
    }
    const int y = ty0 + y4, xo = tx0 + x;
    if (y < OUT_H && xo < OUT_W)
#pragma unroll
        for (int jp = 0; jp < 16; ++jp) {
            const int o = o_base + jp;
            Og[(((size_t)b * NOC + o) * OUT_H + y) * OUT_W + xo] = acc[jp] + Bg[o];
        }
}

extern "C" void kernel_launch(void* const* d_in, const int* in_sizes, int n_in,
                              void* d_out, int out_size, void* d_ws, size_t ws_size,
                              hipStream_t stream)
{
    const float* X = (const float*)d_in[0];
    const float* W = (const float*)d_in[1];
    const float* B = (const float*)d_in[2];
    float* O = (float*)d_out;

    if (ws_size < WS_NEEDED) {   // fallback: proven VALU kernel
        dim3 grid((OUT_W + TILE_X - 1) / TILE_X, (OUT_H + TILE_Y - 1) / TILE_Y, BATCH);
        sconv_kernel<<<grid, 256, 0, stream>>>(X, W, B, O);
        return;
    }

    f16* Ah = (f16*)d_ws;
    f16* Xn = (f16*)((char*)d_ws + XN_OFF);

    build_a_k<<<14, 256, 0, stream>>>(W, Ah);
    transpose_k<<<BATCH * IN_H * 3, 256, 0, stream>>>(X, Xn);
    sconv_mfma<<<NTILES / 2, 256, 0, stream>>>(Ah, Xn, B, O);   // 1128 blocks
}